// Round 10
// baseline (127.170 us; speedup 1.0000x reference)
//
#include <hip/hip_runtime.h>
#include <math.h>

#define NQ 6
#define DIM 64
#define W1S 65           // padded LDS stride (R2-proven)
#define PI_F 3.14159265358979323846f

// ---------- DPP helpers (R2 verbatim) ----------
template <int CTRL, int ROWM, bool BC>
__device__ __forceinline__ float dpp_add_src(float v) {
  int r = __builtin_amdgcn_update_dpp(0, __float_as_int(v), CTRL, ROWM, 0xF, BC);
  return __int_as_float(r);
}

// sum over 64 lanes; valid in lane 63 (R2-proven)
__device__ __forceinline__ float red_sum(float v) {
  v += dpp_add_src<0x111, 0xF, true>(v);   // row_shr:1
  v += dpp_add_src<0x112, 0xF, true>(v);   // row_shr:2
  v += dpp_add_src<0x114, 0xF, true>(v);   // row_shr:4
  v += dpp_add_src<0x118, 0xF, true>(v);   // row_shr:8
  v += dpp_add_src<0x142, 0xA, false>(v);  // row_bcast:15 -> rows 1,3
  v += dpp_add_src<0x143, 0xC, false>(v);  // row_bcast:31 -> rows 2,3
  return v;
}
__device__ __forceinline__ float bcast63(float v) {
  return __int_as_float(__builtin_amdgcn_readlane(__float_as_int(v), 63));
}
__device__ __forceinline__ float rdlane(float v, int l) {
  return __int_as_float(__builtin_amdgcn_readlane(__float_as_int(v), l));
}
__device__ __forceinline__ float bperm(int pa, float v) {
  return __int_as_float(__builtin_amdgcn_ds_bpermute(pa, __float_as_int(v)));
}

// ---------- xor-partner shuffle (R2 verbatim) ----------
template <int W>
__device__ __forceinline__ float sh_partner(float v) {
  if constexpr (W == 5) {        // xor 1: quad_perm [1,0,3,2]
    int i = __float_as_int(v);
    return __int_as_float(__builtin_amdgcn_update_dpp(i, i, 0xB1, 0xF, 0xF, false));
  } else if constexpr (W == 4) { // xor 2: quad_perm [2,3,0,1]
    int i = __float_as_int(v);
    return __int_as_float(__builtin_amdgcn_update_dpp(i, i, 0x4E, 0xF, 0xF, false));
  } else if constexpr (W == 3) { // xor 4
    return __int_as_float(__builtin_amdgcn_ds_swizzle(__float_as_int(v), 0x101F));
  } else if constexpr (W == 2) { // xor 8
    return __int_as_float(__builtin_amdgcn_ds_swizzle(__float_as_int(v), 0x201F));
  } else if constexpr (W == 1) { // xor 16
    return __int_as_float(__builtin_amdgcn_ds_swizzle(__float_as_int(v), 0x401F));
  } else {                       // xor 32
    return __shfl_xor(v, 32, 64);
  }
}

// ---------- one Rot gate on wire W (R2 verbatim) ----------
template <int W>
__device__ __forceinline__ void gate_w(float& re, float& im, float4 c, int lane) {
  float pr = sh_partner<W>(re);
  float pi = sh_partner<W>(im);
  const bool hi = (lane & (32 >> W)) != 0;
  float sa = hi ? -c.y : c.y;
  float sb = hi ? -c.z : c.z;
  float nr = c.x * re;
  nr = fmaf(-sa, im, nr);
  nr = fmaf(sb, pr, nr);
  nr = fmaf(-c.w, pi, nr);
  float ni = c.x * im;
  ni = fmaf(sa, re, ni);
  ni = fmaf(sb, pi, ni);
  ni = fmaf(c.w, pr, ni);
  re = nr; im = ni;
}

// composed source index for the CNOT ring of range r (R2 verbatim)
__device__ __forceinline__ int cnot_src(int j, int r) {
  int i = j;
  #pragma unroll
  for (int w = 5; w >= 0; --w) {
    const int cm = 32 >> w;
    const int tm = 32 >> ((w + r) % NQ);
    if (i & cm) i ^= tm;
  }
  return i;
}

// =====================================================================
// Kernel 1: compose the full circuit unitary U (64x64 complex).
// 16 blocks x 4 waves; each wave evolves one basis column with the
// R2-proven gate machinery and writes U[:,col] to d_ws.
// Layout: uout[col*64 + row] = (re, im)  -> matvec reads u[k*64 + lane].
// =====================================================================
__global__ __launch_bounds__(256) void build_u(
    const float* __restrict__ th_sh,
    const float* __restrict__ th_tk,
    float2* __restrict__ uout)
{
  __shared__ float4 coef[18];
  const int tid = threadIdx.x;
  if (tid < 18) {
    const int layer = tid / 6, w = tid % 6;
    const float* th = (layer < 2) ? (th_sh + (layer * 6 + w) * 3)
                                  : (th_tk + w * 3);
    const float phi = th[0], the = th[1], om = th[2];
    float S, C;   sincosf(0.5f * the,        &S,  &C);
    float sS, cS; sincosf(0.5f * (om + phi), &sS, &cS);
    float sD, cD; sincosf(0.5f * (om - phi), &sD, &cD);
    coef[tid] = make_float4(C * cS, -C * sS, -S * cD, S * sD);
  }
  __syncthreads();

  const int lane = tid & 63;
  const int col = blockIdx.x * 4 + (tid >> 6);   // 0..63
  const int pa1 = cnot_src(lane, 1) << 2;
  const int pa2 = cnot_src(lane, 2) << 2;

  float re = (lane == col) ? 1.0f : 0.0f;
  float im = 0.0f;

  gate_w<0>(re, im, coef[0], lane);
  gate_w<1>(re, im, coef[1], lane);
  gate_w<2>(re, im, coef[2], lane);
  gate_w<3>(re, im, coef[3], lane);
  gate_w<4>(re, im, coef[4], lane);
  gate_w<5>(re, im, coef[5], lane);
  re = bperm(pa1, re); im = bperm(pa1, im);

  gate_w<0>(re, im, coef[6], lane);
  gate_w<1>(re, im, coef[7], lane);
  gate_w<2>(re, im, coef[8], lane);
  gate_w<3>(re, im, coef[9], lane);
  gate_w<4>(re, im, coef[10], lane);
  gate_w<5>(re, im, coef[11], lane);
  re = bperm(pa2, re); im = bperm(pa2, im);

  gate_w<0>(re, im, coef[12], lane);
  gate_w<1>(re, im, coef[13], lane);
  gate_w<2>(re, im, coef[14], lane);
  gate_w<3>(re, im, coef[15], lane);
  gate_w<4>(re, im, coef[16], lane);
  gate_w<5>(re, im, coef[17], lane);
  re = bperm(pa1, re); im = bperm(pa1, im);

  uout[col * 64 + lane] = make_float2(re, im);
}

// =====================================================================
// Kernel 2: encoder + psi0 + U-matvec + measurement (wave-per-element).
// =====================================================================
__global__ __launch_bounds__(256) void qmaml_v10(
    const float* __restrict__ x,
    const float* __restrict__ W1,
    const float* __restrict__ b1,
    const float* __restrict__ ln_g,
    const float* __restrict__ ln_b,
    const float* __restrict__ W2,
    const float* __restrict__ b2,
    const float* __restrict__ Wc,
    const float* __restrict__ bc,
    const float2* __restrict__ uglob,
    float* __restrict__ out,
    int B)
{
  __shared__ float w1t[64 * W1S];   // 16.6 KB, W1^T padded (R2-proven)
  __shared__ float2 uld[4096];      // 32 KB, U: uld[k*64 + i]
  __shared__ float psiw[4][64];     // per-wave psi0 staging

  const int tid = threadIdx.x;

  #pragma unroll
  for (int it = 0; it < 16; ++it) {
    const int idx = tid + it * 256;
    w1t[(idx & 63) * W1S + (idx >> 6)] = W1[idx];
  }
  #pragma unroll
  for (int it = 0; it < 16; ++it) {
    const int idx = tid + it * 256;
    uld[idx] = uglob[idx];
  }
  __syncthreads();

  const int lane = tid & 63;
  const int wv = tid >> 6;
  const int wid = __builtin_amdgcn_readfirstlane(blockIdx.x * 4 + wv);
  const int nw = gridDim.x * 4;

  // ---- batch-independent per-lane preloads (R2 verbatim) ----
  const float b1v = b1[lane];
  const float lgv = ln_g[lane];
  const float lbv = ln_b[lane];
  float w2v[NQ];
  #pragma unroll
  for (int m = 0; m < NQ; ++m) w2v[m] = W2[m * DIM + lane];
  const float b2v = (lane < NQ) ? b2[lane] : 0.0f;
  const float bcv = (lane < 5) ? bc[lane] : 0.0f;
  float g5[5];
  #pragma unroll
  for (int j = 0; j < 5; ++j) {
    float a = 0.0f;
    #pragma unroll
    for (int w = 0; w < NQ; ++w) {
      const float wc = Wc[j * NQ + w];
      a += (lane & (32 >> w)) ? -wc : wc;
    }
    g5[j] = a;
  }

  for (int t = wid; t < B; t += nw) {
    const float* __restrict__ xr =
        x + (size_t)__builtin_amdgcn_readfirstlane(t) * DIM;

    // ---- Linear1 + ReLU: 4 independent fma chains (R9-validated) ----
    float a0 = b1v, a1 = 0.0f, a2 = 0.0f, a3 = 0.0f;
    #pragma unroll
    for (int k = 0; k < DIM; k += 4) {
      a0 = fmaf(w1t[(k + 0) * W1S + lane], xr[k + 0], a0);
      a1 = fmaf(w1t[(k + 1) * W1S + lane], xr[k + 1], a1);
      a2 = fmaf(w1t[(k + 2) * W1S + lane], xr[k + 2], a2);
      a3 = fmaf(w1t[(k + 3) * W1S + lane], xr[k + 3], a3);
    }
    float h = fmaxf((a0 + a1) + (a2 + a3), 0.0f);

    // ---- one-pass LayerNorm (R9-validated) ----
    const float s1 = bcast63(red_sum(h)) * (1.0f / DIM);
    const float s2 = bcast63(red_sum(h * h)) * (1.0f / DIM);
    const float rs = __builtin_amdgcn_rsqf(s2 - s1 * s1 + 1e-5f);
    h = fmaf((h - s1) * rs, lgv, lbv);

    // ---- Linear2 (R2 verbatim) ----
    float y = 0.0f;
    #pragma unroll
    for (int m = 0; m < NQ; ++m) {
      const float r = bcast63(red_sum(w2v[m] * h));
      y = (lane == m) ? r : y;
    }
    y += b2v;

    // ---- tanh + half-angle sincos (R2 verbatim) ----
    const float e = __expf(2.0f * y);
    const float tz = fmaf(-2.0f, __builtin_amdgcn_rcpf(e + 1.0f), 1.0f);
    const float ha = (0.5f * PI_F) * tz;
    const float sv = __sinf(ha);
    const float cv = __cosf(ha);

    // ---- own psi0 amplitude (R2 verbatim), staged for wave broadcast ----
    float a = (lane & 32) ? rdlane(sv, 0) : rdlane(cv, 0);
    a *= (lane & 16) ? rdlane(sv, 1) : rdlane(cv, 1);
    a *= (lane &  8) ? rdlane(sv, 2) : rdlane(cv, 2);
    a *= (lane &  4) ? rdlane(sv, 3) : rdlane(cv, 3);
    a *= (lane &  2) ? rdlane(sv, 4) : rdlane(cv, 4);
    a *= (lane &  1) ? rdlane(sv, 5) : rdlane(cv, 5);
    psiw[wv][lane] = a;
    asm volatile("s_waitcnt lgkmcnt(0)" ::: "memory");

    // ---- psi = U * psi0 (psi0 real): 8 independent fma chains ----
    float r0 = 0.f, r1 = 0.f, r2 = 0.f, r3 = 0.f;
    float i0 = 0.f, i1 = 0.f, i2 = 0.f, i3 = 0.f;
    #pragma unroll
    for (int k4 = 0; k4 < 16; ++k4) {
      const float4 p4 = reinterpret_cast<const float4*>(psiw[wv])[k4];
      const float2 u0 = uld[(4 * k4 + 0) * 64 + lane];
      const float2 u1 = uld[(4 * k4 + 1) * 64 + lane];
      const float2 u2 = uld[(4 * k4 + 2) * 64 + lane];
      const float2 u3 = uld[(4 * k4 + 3) * 64 + lane];
      r0 = fmaf(u0.x, p4.x, r0);  i0 = fmaf(u0.y, p4.x, i0);
      r1 = fmaf(u1.x, p4.y, r1);  i1 = fmaf(u1.y, p4.y, i1);
      r2 = fmaf(u2.x, p4.z, r2);  i2 = fmaf(u2.y, p4.z, i2);
      r3 = fmaf(u3.x, p4.w, r3);  i3 = fmaf(u3.y, p4.w, i3);
    }
    const float rr = (r0 + r1) + (r2 + r3);
    const float ii = (i0 + i1) + (i2 + i3);

    // ---- measurement + classifier head (R2 verbatim) ----
    const float p = fmaf(rr, rr, ii * ii);
    float o0 = bcast63(red_sum(p * g5[0]));
    float o1 = bcast63(red_sum(p * g5[1]));
    float o2 = bcast63(red_sum(p * g5[2]));
    float o3 = bcast63(red_sum(p * g5[3]));
    float o4 = bcast63(red_sum(p * g5[4]));
    float vout = (lane == 0) ? o0 :
                 (lane == 1) ? o1 :
                 (lane == 2) ? o2 :
                 (lane == 3) ? o3 : o4;
    if (lane < 5) out[(size_t)t * 5 + lane] = vout + bcv;
  }
}

extern "C" void kernel_launch(void* const* d_in, const int* in_sizes, int n_in,
                              void* d_out, int out_size, void* d_ws, size_t ws_size,
                              hipStream_t stream) {
  const float* x     = (const float*)d_in[0];
  const float* W1    = (const float*)d_in[1];
  const float* b1    = (const float*)d_in[2];
  const float* ln_g  = (const float*)d_in[3];
  const float* ln_b  = (const float*)d_in[4];
  const float* W2    = (const float*)d_in[5];
  const float* b2    = (const float*)d_in[6];
  const float* th_sh = (const float*)d_in[7];
  const float* th_tk = (const float*)d_in[8];
  const float* Wc    = (const float*)d_in[9];
  const float* bc    = (const float*)d_in[10];
  float* out = (float*)d_out;
  float2* u = (float2*)d_ws;          // 32 KB scratch for the composed unitary

  const int B = in_sizes[0] / DIM;

  build_u<<<16, 256, 0, stream>>>(th_sh, th_tk, u);

  int blocks = (B + 3) / 4;
  if (blocks > 768) blocks = 768;     // 3 blocks/CU (50 KB LDS each)
  qmaml_v10<<<blocks, 256, 0, stream>>>(x, W1, b1, ln_g, ln_b, W2, b2,
                                        Wc, bc, u, out, B);
}